// Round 1
// baseline (257.607 us; speedup 1.0000x reference)
//
#include <hip/hip_runtime.h>
#include <cstddef>

#define NN 1024
#define HF 128
#define DE_ 32
#define SLOPE 0.2f
#define EPSV 1e-5f

// ---------------- Kernel 1: node projections -----------------------------
__global__ __launch_bounds__(256) void proj_kernel(
    const float* __restrict__ x, const float* __restrict__ W_proj,
    const float* __restrict__ W_skip, const float* __restrict__ a_src,
    const float* __restrict__ a_tgt, float* __restrict__ nproj,
    float* __restrict__ skip, float* __restrict__ s_src,
    float* __restrict__ s_tgt)
{
  const int i = blockIdx.x, t = threadIdx.x;
  __shared__ float xs[128];
  if (t < 128) xs[t] = x[(size_t)i * 128 + t];
  __syncthreads();
  const float* W = (t < 128) ? W_proj : W_skip;  // wave-uniform (waves 0-1 vs 2-3)
  const int c = t & 127;
  float acc = 0.f;
#pragma unroll 16
  for (int k = 0; k < 128; ++k) acc = fmaf(xs[k], W[k * 128 + c], acc);
  if (t < 128) nproj[(size_t)i * 128 + c] = acc;
  else         skip[(size_t)i * 128 + c] = acc;
  // s_src / s_tgt: per-head 32-lane reduction over f (threads 0..127 only)
  float vs = 0.f, vt = 0.f;
  if (t < 128) { vs = acc * a_src[c]; vt = acc * a_tgt[c]; }
#pragma unroll
  for (int off = 16; off; off >>= 1) {
    vs += __shfl_down(vs, off, 32);
    vt += __shfl_down(vt, off, 32);
  }
  if (t < 128 && (t & 31) == 0) {
    s_src[i * 4 + (t >> 5)] = vs;
    s_tgt[i * 4 + (t >> 5)] = vt;
  }
}

// ---------------- Kernel 2: sparse fused attention -----------------------
// One block (256 thr) per target row i. Only unmasked (conn==0) neighbors are
// processed: masked entries are exactly 0 after softmax (exp(-1e9-max)==0).
__global__ __launch_bounds__(256) void attn_kernel(
    const float* __restrict__ e,      // [N,N,32]
    const float* __restrict__ conn,   // [N,N]
    const float* __restrict__ W_edge, // [32,128]
    const float* __restrict__ b_edge, // [128]
    const float* __restrict__ a_edge, // [128]
    const float* __restrict__ s_src,  // [N,4]
    const float* __restrict__ s_tgt,  // [N,4]
    const float* __restrict__ nproj,  // [N,128]
    const float* __restrict__ skip,   // [N,128]
    float* __restrict__ out_pre)      // [N,128]
{
  const int i = blockIdx.x, t = threadIdx.x;
  __shared__ unsigned short nbr[NN];
  __shared__ float sc[NN * 4];      // scores then attn weights, [n][h]
  __shared__ float partial[256];
  __shared__ int cnt;

  const int c = t & 127;            // output channel
  const int h = c >> 5;             // head
  const int half = t >> 7;          // 0/1: which half of the neighbor list

  // W_edge column c in registers (reused for every edge of this row)
  float Wc[DE_];
#pragma unroll
  for (int k = 0; k < DE_; ++k) Wc[k] = W_edge[k * 128 + c];
  const float aec = a_edge[c];
  const float bec = b_edge[c];
  const float ssi = s_src[i * 4 + h];

  if (t == 0) cnt = 0;
  __syncthreads();
  // --- compact live-neighbor list (order-free; only perturbs fp assoc.) ---
  for (int j = t; j < NN; j += 256) {
    if (conn[(size_t)i * NN + j] > -0.5f) {
      int p = atomicAdd(&cnt, 1);
      nbr[p] = (unsigned short)j;
    }
  }
  __syncthreads();
  const int M = cnt;

  // --- phase A: per-edge scores -----------------------------------------
  for (int n = half; n < M; n += 2) {
    const int j = nbr[n];
    const float4* ev4 = (const float4*)(e + ((size_t)i << 15) + ((size_t)j << 5));
    float acc = bec;
#pragma unroll
    for (int q = 0; q < 8; ++q) {
      float4 v = ev4[q];
      acc = fmaf(v.x, Wc[4 * q + 0], acc);
      acc = fmaf(v.y, Wc[4 * q + 1], acc);
      acc = fmaf(v.z, Wc[4 * q + 2], acc);
      acc = fmaf(v.w, Wc[4 * q + 3], acc);
    }
    acc = acc > 0.f ? acc : SLOPE * acc;       // leaky on eproj
    float contrib = acc * aec;
#pragma unroll
    for (int off = 16; off; off >>= 1) contrib += __shfl_down(contrib, off, 32);
    if ((c & 31) == 0) {
      float sco = ssi + s_tgt[(size_t)j * 4 + h] + contrib;
      sco = sco > 0.f ? sco : SLOPE * sco;     // leaky on logits
      sc[n * 4 + h] = sco;
    }
  }
  __syncthreads();

  // --- phase B: per-head softmax (one wave per head) --------------------
  {
    const int hh = t >> 6;
    const int lane = t & 63;
    float m = -1e30f;
    for (int n = lane; n < M; n += 64) m = fmaxf(m, sc[n * 4 + hh]);
#pragma unroll
    for (int off = 32; off; off >>= 1) m = fmaxf(m, __shfl_down(m, off, 64));
    m = __shfl(m, 0, 64);
    float s = 0.f;
    for (int n = lane; n < M; n += 64) s += __expf(sc[n * 4 + hh] - m);
#pragma unroll
    for (int off = 32; off; off >>= 1) s += __shfl_down(s, off, 64);
    s = __shfl(s, 0, 64);
    const float inv = 1.f / s;
    for (int n = lane; n < M; n += 64)
      sc[n * 4 + hh] = __expf(sc[n * 4 + hh] - m) * inv;
  }
  __syncthreads();

  // --- phase C: aggregate attn * nproj + skip ---------------------------
  float accum = 0.f;
  for (int n = half; n < M; n += 2) {
    const int j = nbr[n];
    accum = fmaf(sc[n * 4 + h], nproj[(size_t)j * 128 + c], accum);
  }
  partial[t] = accum;
  __syncthreads();
  if (t < 128) {
    float tot = partial[t] + partial[t + 128] + skip[(size_t)i * 128 + t];
    out_pre[(size_t)i * 128 + t] = tot;
  }
}

// ---------------- Kernel 3: BatchNorm + bias + ELU ------------------------
__global__ __launch_bounds__(256) void bn_kernel(
    const float* __restrict__ out_pre, const float* __restrict__ gamma,
    const float* __restrict__ beta, const float* __restrict__ bias,
    float* __restrict__ out)
{
  const int c = blockIdx.x, t = threadIdx.x;
  float vals[4];
  float s = 0.f, s2 = 0.f;
#pragma unroll
  for (int q = 0; q < 4; ++q) {
    float v = out_pre[(size_t)(t + q * 256) * 128 + c];
    vals[q] = v;
    s += v;
    s2 += v * v;
  }
  __shared__ float rs[4], rs2[4], stat[2];
#pragma unroll
  for (int off = 32; off; off >>= 1) {
    s += __shfl_down(s, off, 64);
    s2 += __shfl_down(s2, off, 64);
  }
  if ((t & 63) == 0) { rs[t >> 6] = s; rs2[t >> 6] = s2; }
  __syncthreads();
  if (t == 0) {
    float S = rs[0] + rs[1] + rs[2] + rs[3];
    float S2 = rs2[0] + rs2[1] + rs2[2] + rs2[3];
    float mu = S * (1.f / 1024.f);
    float var = S2 * (1.f / 1024.f) - mu * mu;
    stat[0] = mu;
    stat[1] = rsqrtf(var + EPSV);
  }
  __syncthreads();
  const float mu = stat[0], rstd = stat[1];
  const float g = gamma[c] * rstd;
  const float b = beta[c] + bias[c] - mu * g;
#pragma unroll
  for (int q = 0; q < 4; ++q) {
    float y = vals[q] * g + b;
    out[(size_t)(t + q * 256) * 128 + c] = y > 0.f ? y : expm1f(y);
  }
}

// ---------------- Launch ---------------------------------------------------
extern "C" void kernel_launch(void* const* d_in, const int* in_sizes, int n_in,
                              void* d_out, int out_size, void* d_ws,
                              size_t ws_size, hipStream_t stream)
{
  const float* x      = (const float*)d_in[0];
  const float* e      = (const float*)d_in[1];
  const float* conn   = (const float*)d_in[2];
  const float* W_proj = (const float*)d_in[3];
  const float* W_edge = (const float*)d_in[4];
  const float* b_edge = (const float*)d_in[5];
  const float* a_src  = (const float*)d_in[6];
  const float* a_tgt  = (const float*)d_in[7];
  const float* a_edge = (const float*)d_in[8];
  const float* W_skip = (const float*)d_in[9];
  const float* gamma  = (const float*)d_in[10];
  const float* beta   = (const float*)d_in[11];
  const float* bias   = (const float*)d_in[12];

  // workspace: nproj(128K) | skip(128K) | out_pre(128K) | s_src(4K) | s_tgt(4K) floats
  float* nproj   = (float*)d_ws;
  float* skip    = nproj + (size_t)NN * HF;
  float* out_pre = skip + (size_t)NN * HF;
  float* s_src   = out_pre + (size_t)NN * HF;
  float* s_tgt   = s_src + (size_t)NN * 4;

  proj_kernel<<<NN, 256, 0, stream>>>(x, W_proj, W_skip, a_src, a_tgt,
                                      nproj, skip, s_src, s_tgt);
  attn_kernel<<<NN, 256, 0, stream>>>(e, conn, W_edge, b_edge, a_edge,
                                      s_src, s_tgt, nproj, skip, out_pre);
  bn_kernel<<<HF, 256, 0, stream>>>(out_pre, gamma, beta, bias, (float*)d_out);
}

// Round 2
// 230.752 us; speedup vs baseline: 1.1164x; 1.1164x over previous
//
#include <hip/hip_runtime.h>
#include <cstddef>

#define NN 1024
#define HF 128
#define DE_ 32
#define SLOPE 0.2f
#define EPSV 1e-5f
#define ETILE 64   // edges staged to LDS per tile in attn phase A

// ---------------- Kernel 1: node projections (4 nodes/block) --------------
__global__ __launch_bounds__(256) void proj_kernel(
    const float* __restrict__ x, const float* __restrict__ W_proj,
    const float* __restrict__ W_skip, const float* __restrict__ a_src,
    const float* __restrict__ a_tgt, float* __restrict__ nproj,
    float* __restrict__ skip, float* __restrict__ s_src,
    float* __restrict__ s_tgt)
{
  const int b = blockIdx.x, t = threadIdx.x;     // block handles nodes 4b..4b+3
  __shared__ float xs[4 * 128];
  xs[t] = x[(size_t)b * 512 + t];
  xs[t + 256] = x[(size_t)b * 512 + t + 256];
  __syncthreads();
  const int sel = t >> 7;                        // 0: W_proj/nproj, 1: W_skip/skip
  const float* W = sel ? W_skip : W_proj;        // wave-uniform
  const int c = t & 127;
  float acc0 = 0.f, acc1 = 0.f, acc2 = 0.f, acc3 = 0.f;
#pragma unroll 8
  for (int k = 0; k < 128; ++k) {
    const float w = W[k * 128 + c];
    acc0 = fmaf(xs[k], w, acc0);
    acc1 = fmaf(xs[128 + k], w, acc1);
    acc2 = fmaf(xs[256 + k], w, acc2);
    acc3 = fmaf(xs[384 + k], w, acc3);
  }
  float* dst = sel ? skip : nproj;
  dst[(size_t)(4 * b + 0) * 128 + c] = acc0;
  dst[(size_t)(4 * b + 1) * 128 + c] = acc1;
  dst[(size_t)(4 * b + 2) * 128 + c] = acc2;
  dst[(size_t)(4 * b + 3) * 128 + c] = acc3;
  if (sel == 0) {                                // logits from nproj accs
    const float as = a_src[c], at = a_tgt[c];
    const int h = c >> 5;
    float accs[4] = {acc0, acc1, acc2, acc3};
#pragma unroll
    for (int n = 0; n < 4; ++n) {
      float vs = accs[n] * as, vt = accs[n] * at;
#pragma unroll
      for (int off = 16; off; off >>= 1) {
        vs += __shfl_down(vs, off, 32);
        vt += __shfl_down(vt, off, 32);
      }
      if ((c & 31) == 0) {
        s_src[(4 * b + n) * 4 + h] = vs;
        s_tgt[(4 * b + n) * 4 + h] = vt;
      }
    }
  }
}

// ---------------- Kernel 2: sparse fused attention -----------------------
// One block (256 thr) per target row i. Masked entries are exactly 0 after
// softmax (exp(-1e9-max) underflows), so only conn==0 neighbors matter.
__global__ __launch_bounds__(256) void attn_kernel(
    const float* __restrict__ e,      // [N,N,32]
    const float* __restrict__ conn,   // [N,N]
    const float* __restrict__ W_edge, // [32,128]
    const float* __restrict__ b_edge, // [128]
    const float* __restrict__ a_edge, // [128]
    const float* __restrict__ s_src,  // [N,4]
    const float* __restrict__ s_tgt,  // [N,4]
    const float* __restrict__ nproj,  // [N,128]
    const float* __restrict__ skip,   // [N,128]
    float* __restrict__ out_pre)      // [N,128]
{
  const int i = blockIdx.x, t = threadIdx.x;
  __shared__ unsigned short nbr[NN];
  __shared__ float sc[NN * 4];            // scores -> attn weights, [n][h]
  __shared__ float ebuf[ETILE * 32];      // staged e-rows for current tile
  __shared__ float partial[256];
  __shared__ int cnt;

  const int c = t & 127;                  // output channel
  const int h = c >> 5;                   // head
  const int half = t >> 7;                // 0/1: edge-interleave group

  float Wc[DE_];                          // W_edge column c in registers
#pragma unroll
  for (int k = 0; k < DE_; ++k) Wc[k] = W_edge[k * 128 + c];
  const float aec = a_edge[c];
  const float bec = b_edge[c];
  const float ssi = s_src[i * 4 + h];

  if (t == 0) cnt = 0;
  __syncthreads();
  // --- compact live-neighbor list (order-free; only perturbs fp assoc.) ---
  for (int j = t; j < NN; j += 256) {
    if (conn[(size_t)i * NN + j] > -0.5f) {
      int p = atomicAdd(&cnt, 1);
      nbr[p] = (unsigned short)j;
    }
  }
  __syncthreads();
  const int M = cnt;

  // --- phase A: per-edge scores, LDS-staged tiles -----------------------
  for (int base = 0; base < M; base += ETILE) {
    const int mT = min(ETILE, M - base);
    // cooperative stage: mT rows x 8 float4, all loads in flight at once
    for (int q = t; q < mT * 8; q += 256) {
      const int n = q >> 3, part = q & 7;
      const int j = nbr[base + n];
      ((float4*)ebuf)[q] =
          ((const float4*)(e + ((size_t)i << 15) + ((size_t)j << 5)))[part];
    }
    __syncthreads();
    for (int n = half; n < mT; n += 2) {
      const float4* eb4 = (const float4*)(ebuf + n * 32);  // wave-uniform addr
      float acc = bec;
#pragma unroll
      for (int q = 0; q < 8; ++q) {
        float4 v = eb4[q];
        acc = fmaf(v.x, Wc[4 * q + 0], acc);
        acc = fmaf(v.y, Wc[4 * q + 1], acc);
        acc = fmaf(v.z, Wc[4 * q + 2], acc);
        acc = fmaf(v.w, Wc[4 * q + 3], acc);
      }
      acc = acc > 0.f ? acc : SLOPE * acc;        // leaky on eproj
      float contrib = acc * aec;
#pragma unroll
      for (int off = 16; off; off >>= 1) contrib += __shfl_down(contrib, off, 32);
      if ((c & 31) == 0) {
        const int j = nbr[base + n];
        float sco = ssi + s_tgt[(size_t)j * 4 + h] + contrib;
        sco = sco > 0.f ? sco : SLOPE * sco;      // leaky on logits
        sc[(base + n) * 4 + h] = sco;
      }
    }
    __syncthreads();
  }

  // --- phase B: per-head softmax (one wave per head) --------------------
  {
    const int hh = t >> 6;
    const int lane = t & 63;
    float m = -1e30f;
    for (int n = lane; n < M; n += 64) m = fmaxf(m, sc[n * 4 + hh]);
#pragma unroll
    for (int off = 32; off; off >>= 1) m = fmaxf(m, __shfl_down(m, off, 64));
    m = __shfl(m, 0, 64);
    float s = 0.f;
    for (int n = lane; n < M; n += 64) s += __expf(sc[n * 4 + hh] - m);
#pragma unroll
    for (int off = 32; off; off >>= 1) s += __shfl_down(s, off, 64);
    s = __shfl(s, 0, 64);
    const float inv = 1.f / s;
    for (int n = lane; n < M; n += 64)
      sc[n * 4 + hh] = __expf(sc[n * 4 + hh] - m) * inv;
  }
  __syncthreads();

  // --- phase C: aggregate attn * nproj + skip ---------------------------
  float accum = 0.f;
  for (int n = half; n < M; n += 2) {
    const int j = nbr[n];
    accum = fmaf(sc[n * 4 + h], nproj[(size_t)j * 128 + c], accum);
  }
  partial[t] = accum;
  __syncthreads();
  if (t < 128) {
    float tot = partial[t] + partial[t + 128] + skip[(size_t)i * 128 + t];
    out_pre[(size_t)i * 128 + t] = tot;
  }
}

// ---------------- Kernel 3: BatchNorm + bias + ELU ------------------------
__global__ __launch_bounds__(256) void bn_kernel(
    const float* __restrict__ out_pre, const float* __restrict__ gamma,
    const float* __restrict__ beta, const float* __restrict__ bias,
    float* __restrict__ out)
{
  const int c = blockIdx.x, t = threadIdx.x;
  float vals[4];
  float s = 0.f, s2 = 0.f;
#pragma unroll
  for (int q = 0; q < 4; ++q) {
    float v = out_pre[(size_t)(t + q * 256) * 128 + c];
    vals[q] = v;
    s += v;
    s2 += v * v;
  }
  __shared__ float rs[4], rs2[4], stat[2];
#pragma unroll
  for (int off = 32; off; off >>= 1) {
    s += __shfl_down(s, off, 64);
    s2 += __shfl_down(s2, off, 64);
  }
  if ((t & 63) == 0) { rs[t >> 6] = s; rs2[t >> 6] = s2; }
  __syncthreads();
  if (t == 0) {
    float S = rs[0] + rs[1] + rs[2] + rs[3];
    float S2 = rs2[0] + rs2[1] + rs2[2] + rs2[3];
    float mu = S * (1.f / 1024.f);
    float var = S2 * (1.f / 1024.f) - mu * mu;
    stat[0] = mu;
    stat[1] = rsqrtf(var + EPSV);
  }
  __syncthreads();
  const float mu = stat[0], rstd = stat[1];
  const float g = gamma[c] * rstd;
  const float b = beta[c] + bias[c] - mu * g;
#pragma unroll
  for (int q = 0; q < 4; ++q) {
    float y = vals[q] * g + b;
    out[(size_t)(t + q * 256) * 128 + c] = y > 0.f ? y : expm1f(y);
  }
}

// ---------------- Launch ---------------------------------------------------
extern "C" void kernel_launch(void* const* d_in, const int* in_sizes, int n_in,
                              void* d_out, int out_size, void* d_ws,
                              size_t ws_size, hipStream_t stream)
{
  const float* x      = (const float*)d_in[0];
  const float* e      = (const float*)d_in[1];
  const float* conn   = (const float*)d_in[2];
  const float* W_proj = (const float*)d_in[3];
  const float* W_edge = (const float*)d_in[4];
  const float* b_edge = (const float*)d_in[5];
  const float* a_src  = (const float*)d_in[6];
  const float* a_tgt  = (const float*)d_in[7];
  const float* a_edge = (const float*)d_in[8];
  const float* W_skip = (const float*)d_in[9];
  const float* gamma  = (const float*)d_in[10];
  const float* beta   = (const float*)d_in[11];
  const float* bias   = (const float*)d_in[12];

  float* nproj   = (float*)d_ws;
  float* skip    = nproj + (size_t)NN * HF;
  float* out_pre = skip + (size_t)NN * HF;
  float* s_src   = out_pre + (size_t)NN * HF;
  float* s_tgt   = s_src + (size_t)NN * 4;

  proj_kernel<<<NN / 4, 256, 0, stream>>>(x, W_proj, W_skip, a_src, a_tgt,
                                          nproj, skip, s_src, s_tgt);
  attn_kernel<<<NN, 256, 0, stream>>>(e, conn, W_edge, b_edge, a_edge,
                                      s_src, s_tgt, nproj, skip, out_pre);
  bn_kernel<<<HF, 256, 0, stream>>>(out_pre, gamma, beta, bias, (float*)d_out);
}